// Round 2
// baseline (483.698 us; speedup 1.0000x reference)
//
#include <hip/hip_runtime.h>
#include <math.h>

#define NTHREADS 256

namespace {
constexpr int D   = 128;
constexpr int G   = 32;
constexpr int H   = 8;
constexpr int KNB = 48;
constexpr int KP1 = 49;
constexpr int NN  = 512;

constexpr int KV_STRIDE = 132;  // floats; 528B row: 16B-aligned, bank-offset 4/t
constexpr int F_STRIDE  = 33;   // [t][g], bank (t+g)%32 -> conflict-free lane<->t
constexpr int SC_STRIDE = 52;   // [h][t]
constexpr int P_STRIDE  = 132;  // [h][d], 16B-aligned rows

// union region: f[49*33]=1617 floats  (dead after P3 pass 1)
//   reused as: p[8*132]=1056 | red[256] | agg[128]  -> 1440 <= 1617
constexpr int UNI_FLOATS = KP1 * F_STRIDE;     // 1617
constexpr int P_OFF   = 0;
constexpr int RED_OFF = H * P_STRIDE;          // 1056
constexpr int AGG_OFF = RED_OFF + NTHREADS;    // 1312

constexpr float LOG_LO = -2.302585092994046f;  // ln(0.1)
constexpr float LOG_HI =  1.609437912434100f;  // ln(5.0)
constexpr float GWIDTH = (LOG_HI - LOG_LO) / 31.0f;
constexpr float GCOEFF = -0.5f / (GWIDTH * GWIDTH);
constexpr float PI_OVER_CUT = 3.14159265358979323846f / 5.0f;
}  // namespace

__global__ __launch_bounds__(NTHREADS) void tdt_kernel(
    const float* __restrict__ positions,
    const int*   __restrict__ z,
    const int*   __restrict__ neighbors,
    const float* __restrict__ nmask,
    const float* __restrict__ embedding,
    const float* __restrict__ filt_W,
    const float* __restrict__ filt_b,
    const float* __restrict__ Wq,
    const float* __restrict__ Wk,
    const float* __restrict__ Wv,
    const float* __restrict__ Wo,
    float* __restrict__ out)
{
  __shared__ __align__(16) float s_kv[KP1 * KV_STRIDE];   // 25872 B
  __shared__ __align__(16) float s_uni[UNI_FLOATS];       //  6468 B
  __shared__ __align__(16) float s_qk[H * D];             //  4096 B  [h][d]
  __shared__ float s_sc[H * SC_STRIDE];                   //  1664 B
  __shared__ float s_x[D];
  __shared__ float s_q[D];
  __shared__ float s_C[KP1];
  __shared__ float s_mask[KP1];
  __shared__ float s_lr[KP1];
  __shared__ int   s_zj[KP1];

  const int a   = blockIdx.x;
  const int b   = a >> 9;
  const int n   = a & (NN - 1);
  const int tid = threadIdx.x;

  // ---- P0: center embedding ----
  if (tid < D) s_x[tid] = embedding[z[a] * D + tid];

  // ---- P1: geometry ----
  if (tid < KP1) {
    int j; float m;
    if (tid == 0) { j = n; m = 1.0f; }
    else { j = neighbors[a * KNB + tid - 1]; m = nmask[a * KNB + tid - 1]; }
    float r;
    if (tid == 0) r = 0.01f;
    else {
      const float dx = positions[(b * NN + j) * 3 + 0] - positions[a * 3 + 0];
      const float dy = positions[(b * NN + j) * 3 + 1] - positions[a * 3 + 1];
      const float dz = positions[(b * NN + j) * 3 + 2] - positions[a * 3 + 2];
      r = sqrtf(dx * dx + dy * dy + dz * dz + 1e-12f);
    }
    s_lr[tid]   = __logf(r);
    s_C[tid]    = (r < 5.0f) ? (0.5f * (__cosf(r * PI_OVER_CUT) + 1.0f)) : 0.0f;
    s_mask[tid] = m;
    s_zj[tid]   = z[b * NN + j];
  }
  __syncthreads();

  // ---- P2: smearing features f[t][g] ----
  for (int i = tid; i < KP1 * G; i += NTHREADS) {
    const int t = i >> 5;
    const int g = i & 31;
    const float dlt = s_lr[t] - (LOG_LO + (float)g * GWIDTH);
    s_uni[t * F_STRIDE + g] = __expf(GCOEFF * dlt * dlt);
  }
  __syncthreads();

  // ---- P3 pass 1: W[t][c] = f[t][:] @ filt_W[:,c] + filt_b[c], t-in-lane ----
  {
    const int lane_t = tid & 63;
    const bool valid = lane_t < KP1;
    const int tt = valid ? lane_t : 0;
    const int c0 = __builtin_amdgcn_readfirstlane((tid >> 6) * 32);
    float acc[32];
#pragma unroll
    for (int cc = 0; cc < 32; ++cc) acc[cc] = filt_b[c0 + cc];  // scalar loads
    for (int g = 0; g < G; ++g) {
      const float fv = s_uni[tt * F_STRIDE + g];
      const float* wr = &filt_W[g * D + c0];                    // wave-uniform
#pragma unroll
      for (int cc = 0; cc < 32; ++cc) acc[cc] = fmaf(fv, wr[cc], acc[cc]);
    }
    if (valid) {
      const float cf = s_C[lane_t];
#pragma unroll
      for (int cc = 0; cc < 32; cc += 4) {
        float4 v = make_float4(acc[cc] * cf, acc[cc + 1] * cf,
                               acc[cc + 2] * cf, acc[cc + 3] * cf);
        *(float4*)&s_kv[lane_t * KV_STRIDE + c0 + cc] = v;
      }
    }
  }
  __syncthreads();

  // ---- P3 pass 2: kv[t][d] *= emb[zj[t]][d]  (coalesced) ----
  for (int i = tid; i < KP1 * 32; i += NTHREADS) {
    const int t  = i >> 5;
    const int d4 = (i & 31) * 4;
    float4 kvv = *(const float4*)&s_kv[t * KV_STRIDE + d4];
    const float4 ev = *(const float4*)&embedding[s_zj[t] * D + d4];
    kvv.x *= ev.x; kvv.y *= ev.y; kvv.z *= ev.z; kvv.w *= ev.w;
    *(float4*)&s_kv[t * KV_STRIDE + d4] = kvv;
  }
  __syncthreads();

  // ---- P4: q = x @ Wq, full-width split-K ----
  {
    const int d  = tid & (D - 1);
    const int e0 = (tid >> 7) * 64;
    float a0 = 0.f, a1 = 0.f, a2 = 0.f, a3 = 0.f;
    for (int e = e0; e < e0 + 64; e += 4) {
      a0 = fmaf(s_x[e + 0], Wq[(e + 0) * D + d], a0);
      a1 = fmaf(s_x[e + 1], Wq[(e + 1) * D + d], a1);
      a2 = fmaf(s_x[e + 2], Wq[(e + 2) * D + d], a2);
      a3 = fmaf(s_x[e + 3], Wq[(e + 3) * D + d], a3);
    }
    s_uni[RED_OFF + tid] = (a0 + a1) + (a2 + a3);
  }
  __syncthreads();
  if (tid < D) s_q[tid] = s_uni[RED_OFF + tid] + s_uni[RED_OFF + 128 + tid];
  __syncthreads();

  // ---- P5: qk[h][d] = sum_e Wk[d][h*16+e]*q[h*16+e], coalesced + shfl ----
  {
    const int c  = tid & (D - 1);
    const int d0 = (tid >> 7) * 64;
    const int h  = c >> 4;
    const float qv = s_q[c];
    for (int d = d0; d < d0 + 64; ++d) {
      float p = Wk[d * D + c] * qv;     // coalesced over c
      p += __shfl_xor(p, 1);
      p += __shfl_xor(p, 2);
      p += __shfl_xor(p, 4);
      p += __shfl_xor(p, 8);
      if ((c & 15) == 0) s_qk[h * D + d] = p;
    }
  }
  __syncthreads();

  // ---- P6: scores[h][t] = kv[t][:] . qk[h][:] / 4, float4 ----
#pragma unroll
  for (int iter = 0; iter < 2; ++iter) {
    const int i = tid + iter * NTHREADS;
    if (i < KP1 * H) {
      const int t = i >> 3;
      const int h = i & 7;
      const float4* kvp = (const float4*)&s_kv[t * KV_STRIDE];
      const float4* qkp = (const float4*)&s_qk[h * D];
      float a0 = 0.f, a1 = 0.f, a2 = 0.f, a3 = 0.f;
      for (int j = 0; j < 32; ++j) {
        const float4 kv4 = kvp[j];
        const float4 qk4 = qkp[j];
        a0 = fmaf(kv4.x, qk4.x, a0);
        a1 = fmaf(kv4.y, qk4.y, a1);
        a2 = fmaf(kv4.z, qk4.z, a2);
        a3 = fmaf(kv4.w, qk4.w, a3);
      }
      float sc = ((a0 + a1) + (a2 + a3)) * 0.25f;
      if (s_mask[t] <= 0.0f) sc = -1e9f;
      s_sc[h * SC_STRIDE + t] = sc;
    }
  }
  __syncthreads();

  // ---- P7: softmax per head, 8 lanes per head ----
  if (tid < 64) {
    const int h  = tid >> 3;
    const int sl = tid & 7;
    float* row = &s_sc[h * SC_STRIDE];
    float m = -1e30f;
    for (int t = sl; t < KP1; t += 8) m = fmaxf(m, row[t]);
    m = fmaxf(m, __shfl_xor(m, 1));
    m = fmaxf(m, __shfl_xor(m, 2));
    m = fmaxf(m, __shfl_xor(m, 4));
    float s = 0.0f;
    for (int t = sl; t < KP1; t += 8) {
      const float e = __expf(row[t] - m);
      row[t] = e;
      s += e;
    }
    s += __shfl_xor(s, 1);
    s += __shfl_xor(s, 2);
    s += __shfl_xor(s, 4);
    const float inv = 1.0f / s;
    for (int t = sl; t < KP1; t += 8) row[t] *= inv;
  }
  __syncthreads();

  // ---- P8: p[h][d] = sum_t attn[h][t] * kv[t][d], float4 ----
  {
    const int d4 = (tid & 31) * 4;
    const int h  = tid >> 5;
    const float* scr = &s_sc[h * SC_STRIDE];
    float4 acc = make_float4(0.f, 0.f, 0.f, 0.f);
    for (int t = 0; t < KP1; ++t) {
      const float w = scr[t];
      const float4 kv4 = *(const float4*)&s_kv[t * KV_STRIDE + d4];
      acc.x = fmaf(w, kv4.x, acc.x);
      acc.y = fmaf(w, kv4.y, acc.y);
      acc.z = fmaf(w, kv4.z, acc.z);
      acc.w = fmaf(w, kv4.w, acc.w);
    }
    *(float4*)&s_uni[P_OFF + h * P_STRIDE + d4] = acc;
  }
  __syncthreads();

  // ---- P9: agg[c] = sum_d p[h(c)][d] * Wv[d][c], full-width split-K ----
  {
    const int c  = tid & (D - 1);
    const int d0 = (tid >> 7) * 64;
    const float* pr = &s_uni[P_OFF + (c >> 4) * P_STRIDE];
    float a0 = 0.f, a1 = 0.f, a2 = 0.f, a3 = 0.f;
    for (int d = d0; d < d0 + 64; d += 4) {
      const float4 p4 = *(const float4*)&pr[d];
      a0 = fmaf(p4.x, Wv[(d + 0) * D + c], a0);
      a1 = fmaf(p4.y, Wv[(d + 1) * D + c], a1);
      a2 = fmaf(p4.z, Wv[(d + 2) * D + c], a2);
      a3 = fmaf(p4.w, Wv[(d + 3) * D + c], a3);
    }
    s_uni[RED_OFF + tid] = (a0 + a1) + (a2 + a3);
  }
  __syncthreads();
  if (tid < D)
    s_uni[AGG_OFF + tid] = s_uni[RED_OFF + tid] + s_uni[RED_OFF + 128 + tid];
  __syncthreads();

  // ---- P10: out = x + agg @ Wo, full-width split-K ----
  {
    const int c  = tid & (D - 1);
    const int e0 = (tid >> 7) * 64;
    float a0 = 0.f, a1 = 0.f, a2 = 0.f, a3 = 0.f;
    for (int e = e0; e < e0 + 64; e += 4) {
      const float4 g4 = *(const float4*)&s_uni[AGG_OFF + e];
      a0 = fmaf(g4.x, Wo[(e + 0) * D + c], a0);
      a1 = fmaf(g4.y, Wo[(e + 1) * D + c], a1);
      a2 = fmaf(g4.z, Wo[(e + 2) * D + c], a2);
      a3 = fmaf(g4.w, Wo[(e + 3) * D + c], a3);
    }
    s_uni[RED_OFF + tid] = (a0 + a1) + (a2 + a3);
  }
  __syncthreads();
  if (tid < D)
    out[a * D + tid] =
        s_x[tid] + s_uni[RED_OFF + tid] + s_uni[RED_OFF + 128 + tid];
}

extern "C" void kernel_launch(void* const* d_in, const int* in_sizes, int n_in,
                              void* d_out, int out_size, void* d_ws, size_t ws_size,
                              hipStream_t stream) {
  const float* positions = (const float*)d_in[0];
  const int*   z         = (const int*)d_in[1];
  const int*   neighbors = (const int*)d_in[2];
  const float* nmask     = (const float*)d_in[3];
  const float* embedding = (const float*)d_in[4];
  const float* filt_W    = (const float*)d_in[5];
  const float* filt_b    = (const float*)d_in[6];
  const float* Wq        = (const float*)d_in[7];
  const float* Wk        = (const float*)d_in[8];
  const float* Wv        = (const float*)d_in[9];
  const float* Wo        = (const float*)d_in[10];
  float* out = (float*)d_out;

  const int natoms = in_sizes[1];  // B*N = 8192
  tdt_kernel<<<natoms, NTHREADS, 0, stream>>>(
      positions, z, neighbors, nmask, embedding, filt_W, filt_b,
      Wq, Wk, Wv, Wo, out);
}

// Round 3
// 216.160 us; speedup vs baseline: 2.2377x; 2.2377x over previous
//
#include <hip/hip_runtime.h>
#include <math.h>

#define NTHREADS 256

typedef _Float16 h2_t __attribute__((ext_vector_type(2)));

namespace {
constexpr int D   = 128;
constexpr int G   = 32;
constexpr int H   = 8;
constexpr int KNB = 48;
constexpr int KP1 = 49;
constexpr int NN  = 512;

constexpr int KV_H = 136;   // halves per kv row (272 B, 16B-aligned, bank-offset 4/row)
constexpr int QK_H = 136;   // halves per qk row
constexpr int SC_S = 52;    // fp32 scores row stride
constexpr int P_S  = 132;   // fp32 p row stride

constexpr float LOG_LO = -2.302585092994046f;  // ln(0.1)
constexpr float LOG_HI =  1.609437912434100f;  // ln(5.0)
constexpr float GWIDTH = (LOG_HI - LOG_LO) / 31.0f;
constexpr float GCOEFF = -0.5f / (GWIDTH * GWIDTH);
constexpr float PI_OVER_CUT = 3.14159265358979323846f / 5.0f;
}  // namespace

// fp16x2 dot-accumulate: v_dot2_f32_f16 when available, else cvt+fma.
static __device__ __forceinline__ float dot2acc(unsigned ua, unsigned ub, float c) {
  h2_t a, b;
  __builtin_memcpy(&a, &ua, 4);
  __builtin_memcpy(&b, &ub, 4);
#if __has_builtin(__builtin_amdgcn_fdot2)
  return __builtin_amdgcn_fdot2(a, b, c, false);
#else
  c = fmaf((float)a.x, (float)b.x, c);
  c = fmaf((float)a.y, (float)b.y, c);
  return c;
#endif
}

static __device__ __forceinline__ void h2unpack(unsigned u, float& lo, float& hi) {
  h2_t a;
  __builtin_memcpy(&a, &u, 4);
  lo = (float)a.x;
  hi = (float)a.y;
}

__global__ __launch_bounds__(NTHREADS, 4) void tdt_kernel(
    const float* __restrict__ positions,
    const int*   __restrict__ z,
    const int*   __restrict__ neighbors,
    const float* __restrict__ nmask,
    const float* __restrict__ embedding,
    const float* __restrict__ filt_W,
    const float* __restrict__ filt_b,
    const float* __restrict__ Wq,
    const float* __restrict__ Wk,
    const float* __restrict__ Wv,
    const float* __restrict__ Wo,
    float* __restrict__ out)
{
  __shared__ __align__(16) _Float16 s_kvh[KP1 * KV_H];  // 13328 B, fp16 kv
  __shared__ __align__(16) _Float16 s_qkh[H * QK_H];    //  2176 B, fp16 qk [h][d]
  __shared__ __align__(16) float s_q[D];                //   512 B
  __shared__ float s_sc[H * SC_S];                      //  1664 B
  __shared__ __align__(16) float s_p[H * P_S];          //  4224 B
  __shared__ float s_agg[D];                            //   512 B
  __shared__ float s_lr[KP1];
  __shared__ float s_C[KP1];
  __shared__ float s_mask[KP1];
  __shared__ int   s_zj[KP1];

  const int a   = blockIdx.x;
  const int b   = a >> 9;           // NN = 512
  const int n   = a & (NN - 1);
  const int tid = threadIdx.x;

  const int zc = __builtin_amdgcn_readfirstlane(z[a]);  // center species (uniform)

  // ---- Phase A: geometry (tid<49)  ||  P4: q = x @ Wq (tid>=128) ----
  if (tid < KP1) {
    int j; float m;
    if (tid == 0) { j = n; m = 1.0f; }
    else { j = neighbors[a * KNB + tid - 1]; m = nmask[a * KNB + tid - 1]; }
    float r;
    if (tid == 0) r = 0.01f;
    else {
      const float dx = positions[(b * NN + j) * 3 + 0] - positions[a * 3 + 0];
      const float dy = positions[(b * NN + j) * 3 + 1] - positions[a * 3 + 1];
      const float dz = positions[(b * NN + j) * 3 + 2] - positions[a * 3 + 2];
      r = sqrtf(dx * dx + dy * dy + dz * dz + 1e-12f);
    }
    s_lr[tid]   = __logf(r);
    s_C[tid]    = (r < 5.0f) ? (0.5f * (__cosf(r * PI_OVER_CUT) + 1.0f)) : 0.0f;
    s_mask[tid] = m;
    s_zj[tid]   = z[b * NN + j];
  }
  if (tid >= 128) {
    // x[e] is wave-uniform (embedding[zc] row) -> scalar loads; Wq coalesced.
    const int d = tid - 128;
    float acc = 0.0f;
    for (int e = 0; e < D; e += 4) {
      const float x0 = embedding[zc * D + e + 0];
      const float x1 = embedding[zc * D + e + 1];
      const float x2 = embedding[zc * D + e + 2];
      const float x3 = embedding[zc * D + e + 3];
      acc = fmaf(x0, Wq[(e + 0) * D + d], acc);
      acc = fmaf(x1, Wq[(e + 1) * D + d], acc);
      acc = fmaf(x2, Wq[(e + 2) * D + d], acc);
      acc = fmaf(x3, Wq[(e + 3) * D + d], acc);
    }
    s_q[d] = acc;
  }
  __syncthreads();

  // ---- Phase B: P3 filter+kv (fp16, t-in-lane, gaussians in registers) ----
  {
    const int t  = tid & 63;
    const int c0 = __builtin_amdgcn_readfirstlane((tid >> 6) * 32);
    if (t < KP1) {
      const float lr = s_lr[t];
      const float cf = s_C[t];
      const int   zj = s_zj[t];
      float acc[32];
#pragma unroll
      for (int cc = 0; cc < 32; ++cc) acc[cc] = filt_b[c0 + cc];  // uniform s_load
      for (int g = 0; g < G; ++g) {
        const float dlt = lr - (LOG_LO + (float)g * GWIDTH);
        const float fv  = __expf(GCOEFF * dlt * dlt);
        const float* wr = &filt_W[g * D + c0];                    // uniform s_load
#pragma unroll
        for (int cc = 0; cc < 32; ++cc) acc[cc] = fmaf(fv, wr[cc], acc[cc]);
      }
      // embedding gather (VMEM), multiply, convert fp16, b128 LDS writes
      const float* erow = &embedding[(size_t)zj * D + c0];
      float ev[32];
#pragma unroll
      for (int j = 0; j < 8; ++j)
        *(float4*)&ev[j * 4] = *(const float4*)&erow[j * 4];
      union U8 { _Float16 h[8]; uint4 u; };
#pragma unroll
      for (int j = 0; j < 4; ++j) {
        U8 pk;
#pragma unroll
        for (int kk = 0; kk < 8; ++kk)
          pk.h[kk] = (_Float16)(acc[j * 8 + kk] * cf * ev[j * 8 + kk]);
        *(uint4*)&s_kvh[t * KV_H + c0 + j * 8] = pk.u;
      }
    }
  }

  // ---- P5: qk[h][d] = sum_e Wk[d][h*16+e] * q[h*16+e], shuffle-free ----
  {
    const int h = tid & 7;     // all 4 outputs of this thread share h
    const float4 q0 = *(const float4*)&s_q[h * 16 + 0];
    const float4 q1 = *(const float4*)&s_q[h * 16 + 4];
    const float4 q2 = *(const float4*)&s_q[h * 16 + 8];
    const float4 q3 = *(const float4*)&s_q[h * 16 + 12];
#pragma unroll
    for (int it = 0; it < 4; ++it) {
      const int d = ((it * NTHREADS + tid) >> 3);      // each (d,h) exactly once
      const float* wk = &Wk[d * D + h * 16];
      const float4 w0 = *(const float4*)&wk[0];
      const float4 w1 = *(const float4*)&wk[4];
      const float4 w2 = *(const float4*)&wk[8];
      const float4 w3 = *(const float4*)&wk[12];
      float s = w0.x * q0.x;
      s = fmaf(w0.y, q0.y, s); s = fmaf(w0.z, q0.z, s); s = fmaf(w0.w, q0.w, s);
      s = fmaf(w1.x, q1.x, s); s = fmaf(w1.y, q1.y, s);
      s = fmaf(w1.z, q1.z, s); s = fmaf(w1.w, q1.w, s);
      s = fmaf(w2.x, q2.x, s); s = fmaf(w2.y, q2.y, s);
      s = fmaf(w2.z, q2.z, s); s = fmaf(w2.w, q2.w, s);
      s = fmaf(w3.x, q3.x, s); s = fmaf(w3.y, q3.y, s);
      s = fmaf(w3.z, q3.z, s); s = fmaf(w3.w, q3.w, s);
      s_qkh[h * QK_H + d] = (_Float16)s;
    }
  }
  __syncthreads();

  // ---- P6: scores[h][t] = kv[t][:] . qk[h][:] / 4  (fp16 dot2) ----
  {
    const int t  = tid & 63;
    const int h0 = (tid >> 6) * 2;   // wave handles 2 heads; qk reads broadcast
    if (t < KP1) {
      const unsigned* kvr = (const unsigned*)&s_kvh[t * KV_H];
      const unsigned* qk0 = (const unsigned*)&s_qkh[h0 * QK_H];
      const unsigned* qk1 = (const unsigned*)&s_qkh[(h0 + 1) * QK_H];
      float a0 = 0.0f, a1 = 0.0f;
      for (int k = 0; k < 16; ++k) {
        const uint4 kv4 = *(const uint4*)&kvr[k * 4];
        const uint4 u0  = *(const uint4*)&qk0[k * 4];
        const uint4 u1  = *(const uint4*)&qk1[k * 4];
        a0 = dot2acc(kv4.x, u0.x, a0);
        a0 = dot2acc(kv4.y, u0.y, a0);
        a0 = dot2acc(kv4.z, u0.z, a0);
        a0 = dot2acc(kv4.w, u0.w, a0);
        a1 = dot2acc(kv4.x, u1.x, a1);
        a1 = dot2acc(kv4.y, u1.y, a1);
        a1 = dot2acc(kv4.z, u1.z, a1);
        a1 = dot2acc(kv4.w, u1.w, a1);
      }
      const bool live = s_mask[t] > 0.0f;
      s_sc[h0 * SC_S + t]       = live ? a0 * 0.25f : -1e9f;
      s_sc[(h0 + 1) * SC_S + t] = live ? a1 * 0.25f : -1e9f;
    }
  }
  __syncthreads();

  // ---- P7: softmax per head, 8 lanes/head ----
  if (tid < 64) {
    const int h  = tid >> 3;
    const int sl = tid & 7;
    float* row = &s_sc[h * SC_S];
    float m = -1e30f;
    for (int t = sl; t < KP1; t += 8) m = fmaxf(m, row[t]);
    m = fmaxf(m, __shfl_xor(m, 1));
    m = fmaxf(m, __shfl_xor(m, 2));
    m = fmaxf(m, __shfl_xor(m, 4));
    float s = 0.0f;
    for (int t = sl; t < KP1; t += 8) {
      const float e = __expf(row[t] - m);
      row[t] = e;
      s += e;
    }
    s += __shfl_xor(s, 1);
    s += __shfl_xor(s, 2);
    s += __shfl_xor(s, 4);
    const float inv = 1.0f / s;
    for (int t = sl; t < KP1; t += 8) row[t] *= inv;
  }
  __syncthreads();

  // ---- P8: p[h][d] = sum_t attn[h][t] * kv[t][d] ----
  if (tid < 128) {
    const int h = tid >> 4;
    const int k = tid & 15;          // owns halves 8k..8k+7 of every row
    const unsigned* base = (const unsigned*)s_kvh;
    const float* scr = &s_sc[h * SC_S];
    float acc[8];
#pragma unroll
    for (int i = 0; i < 8; ++i) acc[i] = 0.0f;
    for (int t = 0; t < KP1; ++t) {
      const float w = scr[t];
      const uint4 kv4 = *(const uint4*)&base[t * (KV_H / 2) + k * 4];
      float l0, h0v, l1, h1v, l2, h2v, l3, h3v;
      h2unpack(kv4.x, l0, h0v);
      h2unpack(kv4.y, l1, h1v);
      h2unpack(kv4.z, l2, h2v);
      h2unpack(kv4.w, l3, h3v);
      acc[0] = fmaf(w, l0, acc[0]);  acc[1] = fmaf(w, h0v, acc[1]);
      acc[2] = fmaf(w, l1, acc[2]);  acc[3] = fmaf(w, h1v, acc[3]);
      acc[4] = fmaf(w, l2, acc[4]);  acc[5] = fmaf(w, h2v, acc[5]);
      acc[6] = fmaf(w, l3, acc[6]);  acc[7] = fmaf(w, h3v, acc[7]);
    }
    *(float4*)&s_p[h * P_S + k * 8 + 0] =
        make_float4(acc[0], acc[1], acc[2], acc[3]);
    *(float4*)&s_p[h * P_S + k * 8 + 4] =
        make_float4(acc[4], acc[5], acc[6], acc[7]);
  }
  __syncthreads();

  // ---- P9: agg[c] = sum_d p[h(c)][d] * Wv[d][c] ----
  if (tid < 128) {
    const int c = tid;
    const float* pr = &s_p[(c >> 4) * P_S];
    float acc = 0.0f;
    for (int d = 0; d < D; d += 4) {
      const float4 p4 = *(const float4*)&pr[d];
      acc = fmaf(p4.x, Wv[(d + 0) * D + c], acc);
      acc = fmaf(p4.y, Wv[(d + 1) * D + c], acc);
      acc = fmaf(p4.z, Wv[(d + 2) * D + c], acc);
      acc = fmaf(p4.w, Wv[(d + 3) * D + c], acc);
    }
    s_agg[c] = acc;
  }
  __syncthreads();

  // ---- P10: out = x + agg @ Wo ----
  if (tid < 128) {
    const int c = tid;
    float acc = embedding[zc * D + c];   // residual x (row 0 is zero in table)
    for (int e = 0; e < D; e += 4) {
      const float4 g4 = *(const float4*)&s_agg[e];
      acc = fmaf(g4.x, Wo[(e + 0) * D + c], acc);
      acc = fmaf(g4.y, Wo[(e + 1) * D + c], acc);
      acc = fmaf(g4.z, Wo[(e + 2) * D + c], acc);
      acc = fmaf(g4.w, Wo[(e + 3) * D + c], acc);
    }
    out[a * D + c] = acc;
  }
}

extern "C" void kernel_launch(void* const* d_in, const int* in_sizes, int n_in,
                              void* d_out, int out_size, void* d_ws, size_t ws_size,
                              hipStream_t stream) {
  const float* positions = (const float*)d_in[0];
  const int*   z         = (const int*)d_in[1];
  const int*   neighbors = (const int*)d_in[2];
  const float* nmask     = (const float*)d_in[3];
  const float* embedding = (const float*)d_in[4];
  const float* filt_W    = (const float*)d_in[5];
  const float* filt_b    = (const float*)d_in[6];
  const float* Wq        = (const float*)d_in[7];
  const float* Wk        = (const float*)d_in[8];
  const float* Wv        = (const float*)d_in[9];
  const float* Wo        = (const float*)d_in[10];
  float* out = (float*)d_out;

  const int natoms = in_sizes[1];  // B*N = 8192
  tdt_kernel<<<natoms, NTHREADS, 0, stream>>>(
      positions, z, neighbors, nmask, embedding, filt_W, filt_b,
      Wq, Wk, Wv, Wo, out);
}

// Round 4
// 183.033 us; speedup vs baseline: 2.6427x; 1.1810x over previous
//
#include <hip/hip_runtime.h>
#include <math.h>

#define NTHREADS 256

typedef _Float16 v8h __attribute__((ext_vector_type(8)));
typedef float    v4f __attribute__((ext_vector_type(4)));

namespace {
constexpr int D   = 128;
constexpr int H   = 8;
constexpr int KNB = 48;
constexpr int KP1 = 49;
constexpr int NN  = 512;

constexpr int KV_S = 136;   // halves per kv row (272 B; b128 reads 2-way = free)
constexpr int QK_S = 136;   // halves per qk row
constexpr int FWT_S = 40;   // halves per fWT row (80 B; 2-way on b128 = free)
constexpr int ATH_S = 64;   // halves per attn row (K padded to 64)
constexpr int SC_S = 52;    // floats per score row
constexpr int P_S  = 132;   // floats per p row

// ---- manual LDS map (bytes) ----
constexpr int OFF_KV  = 0;              // 64*136 f16 = 17408 (rows 49..63 zeroed)
constexpr int OFF_FWT = 17408;          // 128*40 f16 = 10240  [alias: p, agg]
constexpr int OFF_P   = 17408;          //  8*132 f32 = 4224   (after P3 dead)
constexpr int OFF_AGG = 21632;          //  128 f32   = 512
constexpr int OFF_QK  = 27648;          // 16*136 f16 = 4352  (rows 8..15 unused)
constexpr int OFF_ATH = 32000;          // 16*64  f16 = 2048  (rows 8..15 unused)
constexpr int OFF_SC  = 34048;          //  8*52  f32 = 1664
constexpr int OFF_Q   = 35712;          //  128   f32 = 512
constexpr int OFF_LR  = 36224;          //  49 f32 (pad 208 B)
constexpr int OFF_C   = 36432;
constexpr int OFF_MSK = 36640;
constexpr int OFF_ZJ  = 36848;
constexpr int SMEM_BYTES = 37056;

constexpr float LOG_LO = -2.302585092994046f;  // ln(0.1)
constexpr float LOG_HI =  1.609437912434100f;  // ln(5.0)
constexpr float GWIDTH = (LOG_HI - LOG_LO) / 31.0f;
constexpr float GCOEFF = -0.5f / (GWIDTH * GWIDTH);
constexpr float PI_OVER_CUT = 3.14159265358979323846f / 5.0f;
}  // namespace

__global__ __launch_bounds__(NTHREADS, 4) void tdt_kernel(
    const float* __restrict__ positions,
    const int*   __restrict__ z,
    const int*   __restrict__ neighbors,
    const float* __restrict__ nmask,
    const float* __restrict__ embedding,
    const float* __restrict__ filt_W,
    const float* __restrict__ filt_b,
    const float* __restrict__ Wq,
    const float* __restrict__ Wk,
    const float* __restrict__ Wv,
    const float* __restrict__ Wo,
    float* __restrict__ out)
{
  __shared__ __align__(16) char smem[SMEM_BYTES];
  _Float16* s_kvh = reinterpret_cast<_Float16*>(smem + OFF_KV);
  _Float16* s_fWT = reinterpret_cast<_Float16*>(smem + OFF_FWT);
  float*    s_p   = reinterpret_cast<float*>(smem + OFF_P);
  float*    s_agg = reinterpret_cast<float*>(smem + OFF_AGG);
  _Float16* s_qkh = reinterpret_cast<_Float16*>(smem + OFF_QK);
  _Float16* s_ath = reinterpret_cast<_Float16*>(smem + OFF_ATH);
  float*    s_sc  = reinterpret_cast<float*>(smem + OFF_SC);
  float*    s_q   = reinterpret_cast<float*>(smem + OFF_Q);
  float*    s_lr  = reinterpret_cast<float*>(smem + OFF_LR);
  float*    s_C   = reinterpret_cast<float*>(smem + OFF_C);
  float*    s_msk = reinterpret_cast<float*>(smem + OFF_MSK);
  int*      s_zj  = reinterpret_cast<int*>(smem + OFF_ZJ);

  const int a   = blockIdx.x;
  const int b   = a >> 9;           // NN = 512
  const int n   = a & (NN - 1);
  const int tid = threadIdx.x;
  const int w    = tid >> 6;        // wave id 0..3
  const int lane = tid & 63;
  const int col  = lane & 15;
  const int quad = lane >> 4;

  const int zc = __builtin_amdgcn_readfirstlane(z[a]);  // center species

  // ================= Phase A (3-way parallel across waves) =================
  if (tid < KP1) {
    // geometry
    int j; float m;
    if (tid == 0) { j = n; m = 1.0f; }
    else { j = neighbors[a * KNB + tid - 1]; m = nmask[a * KNB + tid - 1]; }
    float r;
    if (tid == 0) r = 0.01f;
    else {
      const float dx = positions[(b * NN + j) * 3 + 0] - positions[a * 3 + 0];
      const float dy = positions[(b * NN + j) * 3 + 1] - positions[a * 3 + 1];
      const float dz = positions[(b * NN + j) * 3 + 2] - positions[a * 3 + 2];
      r = sqrtf(dx * dx + dy * dy + dz * dz + 1e-12f);
    }
    s_lr[tid]  = __logf(r);
    s_C[tid]   = (r < 5.0f) ? (0.5f * (__cosf(r * PI_OVER_CUT) + 1.0f)) : 0.0f;
    s_msk[tid] = m;
    s_zj[tid]  = z[b * NN + j];
  } else if (tid >= 64 && tid < 128) {
    // stage filt_W transposed fp16: fWT[c][g]
    const int i = tid - 64;
    for (int rep = 0; rep < 64; ++rep) {
      const int idx = rep * 64 + i;        // coalesced read
      const int g = idx >> 7;
      const int c = idx & 127;
      s_fWT[c * FWT_S + g] = (_Float16)filt_W[idx];
    }
    // zero kv rows 49..63 (P8 reads them against zero-padded attn)
    unsigned* kz = reinterpret_cast<unsigned*>(s_kvh);
    for (int d0 = KP1 * (KV_S / 2) + i; d0 < 64 * (KV_S / 2); d0 += 64)
      kz[d0] = 0u;
  } else if (tid >= 128) {
    // P4: q = x @ Wq (x = embedding[zc] row, wave-uniform -> s_loads)
    const int d = tid - 128;
    float acc = 0.0f;
    for (int e = 0; e < D; e += 4) {
      const float x0 = embedding[zc * D + e + 0];
      const float x1 = embedding[zc * D + e + 1];
      const float x2 = embedding[zc * D + e + 2];
      const float x3 = embedding[zc * D + e + 3];
      acc = fmaf(x0, Wq[(e + 0) * D + d], acc);
      acc = fmaf(x1, Wq[(e + 1) * D + d], acc);
      acc = fmaf(x2, Wq[(e + 2) * D + d], acc);
      acc = fmaf(x3, Wq[(e + 3) * D + d], acc);
    }
    s_q[d] = acc;
  }
  __syncthreads();

  // ================= Phase B: P3 filter GEMM via MFMA + P5 qk ==============
  {
    // A-fragment: f[t][g], t = 16w+col, g = quad*8+j (computed in-register)
    const int trow = 16 * w + col;
    const float lr = s_lr[trow < KP1 ? trow : KP1 - 1];
    v8h afrag;
#pragma unroll
    for (int j = 0; j < 8; ++j) {
      const int g = quad * 8 + j;
      const float dlt = lr - (LOG_LO + (float)g * GWIDTH);
      afrag[j] = (_Float16)__expf(GCOEFF * dlt * dlt);
    }
    v4f acc[8];
#pragma unroll
    for (int nt = 0; nt < 8; ++nt) {
      const v8h bfrag =
          *reinterpret_cast<const v8h*>(&s_fWT[(nt * 16 + col) * FWT_S + quad * 8]);
      v4f zero = {0.0f, 0.0f, 0.0f, 0.0f};
      acc[nt] = __builtin_amdgcn_mfma_f32_16x16x32_f16(afrag, bfrag, zero, 0, 0, 0);
    }
    // epilogue: kv[t][c] = (W + b) * C[t] * emb[zj[t]][c], fp16
    float bv[8];
#pragma unroll
    for (int nt = 0; nt < 8; ++nt) bv[nt] = filt_b[nt * 16 + col];
#pragma unroll
    for (int reg = 0; reg < 4; ++reg) {
      const int t = 16 * w + quad * 4 + reg;
      const bool valid = t < KP1;
      float cf = 0.0f; int zj = 0;
      if (valid) { cf = s_C[t]; zj = s_zj[t]; }
      const float* erow = embedding + (size_t)zj * D;
#pragma unroll
      for (int nt = 0; nt < 8; ++nt) {
        const int c = nt * 16 + col;
        if (valid) {
          const float ev = erow[c];
          const float val = (acc[nt][reg] + bv[nt]) * cf * ev;
          s_kvh[t * KV_S + c] = (_Float16)val;
        }
      }
    }
  }
  // P5: qk[h][d] = sum_e Wk[d][h*16+e] * q[h*16+e]  (fp16 out)
  {
    const int h = tid & 7;
    const float4 q0 = *(const float4*)&s_q[h * 16 + 0];
    const float4 q1 = *(const float4*)&s_q[h * 16 + 4];
    const float4 q2 = *(const float4*)&s_q[h * 16 + 8];
    const float4 q3 = *(const float4*)&s_q[h * 16 + 12];
#pragma unroll
    for (int it = 0; it < 4; ++it) {
      const int d = ((it * NTHREADS + tid) >> 3);
      const float* wk = &Wk[d * D + h * 16];
      const float4 w0 = *(const float4*)&wk[0];
      const float4 w1 = *(const float4*)&wk[4];
      const float4 w2 = *(const float4*)&wk[8];
      const float4 w3 = *(const float4*)&wk[12];
      float s = w0.x * q0.x;
      s = fmaf(w0.y, q0.y, s); s = fmaf(w0.z, q0.z, s); s = fmaf(w0.w, q0.w, s);
      s = fmaf(w1.x, q1.x, s); s = fmaf(w1.y, q1.y, s);
      s = fmaf(w1.z, q1.z, s); s = fmaf(w1.w, q1.w, s);
      s = fmaf(w2.x, q2.x, s); s = fmaf(w2.y, q2.y, s);
      s = fmaf(w2.z, q2.z, s); s = fmaf(w2.w, q2.w, s);
      s = fmaf(w3.x, q3.x, s); s = fmaf(w3.y, q3.y, s);
      s = fmaf(w3.z, q3.z, s); s = fmaf(w3.w, q3.w, s);
      s_qkh[h * QK_S + d] = (_Float16)s;
    }
  }
  __syncthreads();

  // ================= Phase C: P6 scores via MFMA ===========================
  {
    v4f sacc = {0.0f, 0.0f, 0.0f, 0.0f};
#pragma unroll
    for (int ks = 0; ks < 4; ++ks) {
      const v8h afr = *reinterpret_cast<const v8h*>(
          &s_kvh[(16 * w + col) * KV_S + ks * 32 + quad * 8]);
      const v8h bfr = *reinterpret_cast<const v8h*>(
          &s_qkh[col * QK_S + ks * 32 + quad * 8]);
      sacc = __builtin_amdgcn_mfma_f32_16x16x32_f16(afr, bfr, sacc, 0, 0, 0);
    }
    const int h = col;            // D col = n = head
    if (h < H) {
#pragma unroll
      for (int reg = 0; reg < 4; ++reg) {
        const int t = 16 * w + quad * 4 + reg;
        if (t < KP1) {
          float sc = sacc[reg] * 0.25f;
          if (s_msk[t] <= 0.0f) sc = -1e9f;
          s_sc[h * SC_S + t] = sc;
        }
      }
    }
  }
  __syncthreads();

  // ================= Phase D: softmax -> attn fp16 (K zero-padded) =========
  if (tid < 64) {
    const int h  = tid >> 3;
    const int sl = tid & 7;
    float* row = &s_sc[h * SC_S];
    float m = -1e30f;
    for (int t = sl; t < KP1; t += 8) m = fmaxf(m, row[t]);
    m = fmaxf(m, __shfl_xor(m, 1));
    m = fmaxf(m, __shfl_xor(m, 2));
    m = fmaxf(m, __shfl_xor(m, 4));
    float s = 0.0f;
    float ev[7];
#pragma unroll
    for (int i = 0; i < 7; ++i) {
      const int t = sl + i * 8;
      const float e = (t < KP1) ? __expf(row[t] - m) : 0.0f;
      ev[i] = e;
      s += e;
    }
    s += __shfl_xor(s, 1);
    s += __shfl_xor(s, 2);
    s += __shfl_xor(s, 4);
    const float inv = 1.0f / s;
#pragma unroll
    for (int i = 0; i < 7; ++i) {
      const int t = sl + i * 8;
      if (t < KP1) s_ath[h * ATH_S + t] = (_Float16)(ev[i] * inv);
    }
  } else if (tid < 128) {
    // zero attn pad t in [49,64) for h<8
    const int i = tid - 64;
    for (int idx = i; idx < 8 * 15; idx += 64) {
      const int h = idx / 15;
      const int t = KP1 + idx % 15;
      s_ath[h * ATH_S + t] = (_Float16)0.0f;
    }
  }
  __syncthreads();

  // ================= Phase E: P8 p = attn @ kv via MFMA ====================
  {
    const v8h a0 = *reinterpret_cast<const v8h*>(&s_ath[col * ATH_S + quad * 8]);
    const v8h a1 = *reinterpret_cast<const v8h*>(&s_ath[col * ATH_S + 32 + quad * 8]);
#pragma unroll
    for (int nti = 0; nti < 2; ++nti) {
      const int c = (2 * w + nti) * 16 + col;
      v8h b0, b1;
#pragma unroll
      for (int j = 0; j < 8; ++j) {
        b0[j] = s_kvh[(quad * 8 + j) * KV_S + c];
        b1[j] = s_kvh[(32 + quad * 8 + j) * KV_S + c];
      }
      v4f pacc = {0.0f, 0.0f, 0.0f, 0.0f};
      pacc = __builtin_amdgcn_mfma_f32_16x16x32_f16(a0, b0, pacc, 0, 0, 0);
      pacc = __builtin_amdgcn_mfma_f32_16x16x32_f16(a1, b1, pacc, 0, 0, 0);
#pragma unroll
      for (int reg = 0; reg < 4; ++reg) {
        const int h = quad * 4 + reg;   // D row = m = head
        if (h < H) s_p[h * P_S + c] = pacc[reg];
      }
    }
  }
  __syncthreads();

  // ================= Phase F: P9 agg, then P10 out =========================
  if (tid < 128) {
    const int c = tid;
    const float* pr = &s_p[(c >> 4) * P_S];
    float acc = 0.0f;
    for (int d = 0; d < D; d += 4) {
      const float4 p4 = *(const float4*)&pr[d];
      acc = fmaf(p4.x, Wv[(d + 0) * D + c], acc);
      acc = fmaf(p4.y, Wv[(d + 1) * D + c], acc);
      acc = fmaf(p4.z, Wv[(d + 2) * D + c], acc);
      acc = fmaf(p4.w, Wv[(d + 3) * D + c], acc);
    }
    s_agg[c] = acc;
  }
  __syncthreads();

  if (tid < 128) {
    const int c = tid;
    float acc = embedding[zc * D + c];   // residual x
    for (int e = 0; e < D; e += 4) {
      const float4 g4 = *(const float4*)&s_agg[e];
      acc = fmaf(g4.x, Wo[(e + 0) * D + c], acc);
      acc = fmaf(g4.y, Wo[(e + 1) * D + c], acc);
      acc = fmaf(g4.z, Wo[(e + 2) * D + c], acc);
      acc = fmaf(g4.w, Wo[(e + 3) * D + c], acc);
    }
    out[a * D + c] = acc;
  }
}

extern "C" void kernel_launch(void* const* d_in, const int* in_sizes, int n_in,
                              void* d_out, int out_size, void* d_ws, size_t ws_size,
                              hipStream_t stream) {
  const float* positions = (const float*)d_in[0];
  const int*   z         = (const int*)d_in[1];
  const int*   neighbors = (const int*)d_in[2];
  const float* nmask     = (const float*)d_in[3];
  const float* embedding = (const float*)d_in[4];
  const float* filt_W    = (const float*)d_in[5];
  const float* filt_b    = (const float*)d_in[6];
  const float* Wq        = (const float*)d_in[7];
  const float* Wk        = (const float*)d_in[8];
  const float* Wv        = (const float*)d_in[9];
  const float* Wo        = (const float*)d_in[10];
  float* out = (float*)d_out;

  const int natoms = in_sizes[1];  // B*N = 8192
  tdt_kernel<<<natoms, NTHREADS, 0, stream>>>(
      positions, z, neighbors, nmask, embedding, filt_W, filt_b,
      Wq, Wk, Wv, Wo, out);
}